// Round 3
// baseline (1117.916 us; speedup 1.0000x reference)
//
#include <hip/hip_runtime.h>
#include <hip/hip_bf16.h>
#include <math.h>

// Problem constants
namespace {
constexpr int Bn = 8;
constexpr int Hn = 16;
constexpr int Ln = 512;
constexpr int HD = 64;
constexpr int DM = 1024;
constexpr int TL = 1024;  // 2*L
constexpr size_t QS  = (size_t)Bn * Hn * Ln * HD;  // 4,194,304 elems per q/k/v-sized array
constexpr size_t FSz = (size_t)Hn * Ln * Ln;       // 4,194,304 floats per-batch Fs (or Gs), banded
constexpr size_t WN  = (size_t)DM * 3 * DM;        // 3,145,728 W elements
}

typedef __bf16 bf16x8 __attribute__((ext_vector_type(8)));
typedef float f32x4 __attribute__((ext_vector_type(4)));

typedef __attribute__((address_space(1))) void as1_void_t;
typedef __attribute__((address_space(3))) void as3_void_t;

__device__ __forceinline__ void gload_lds16(const void* g, void* l) {
  __builtin_amdgcn_global_load_lds((as1_void_t*)g, (as3_void_t*)l, 16, 0, 0);
}

__device__ __forceinline__ unsigned short f2bf(float f) {
  unsigned int u = __float_as_uint(f);
  u += 0x7fffu + ((u >> 16) & 1u);  // round-to-nearest-even
  return (unsigned short)(u >> 16);
}
__device__ __forceinline__ float bf2f(unsigned short h) {
  return __uint_as_float(((unsigned int)h) << 16);
}

// ---------------------------------------------------------------------------
// conv_x: x (fp32 [4096][1024]) -> xh, xl (bf16 hi/lo, same layout)
// ---------------------------------------------------------------------------
__global__ __launch_bounds__(256) void conv_x(const float* __restrict__ x,
                                              unsigned short* __restrict__ xh,
                                              unsigned short* __restrict__ xl) {
  size_t i = ((size_t)blockIdx.x * 256 + threadIdx.x) * 4;
  float4 v = *(const float4*)(x + i);
  unsigned short h0 = f2bf(v.x), h1 = f2bf(v.y), h2 = f2bf(v.z), h3 = f2bf(v.w);
  ushort4 hv = make_ushort4(h0, h1, h2, h3);
  ushort4 lv = make_ushort4(f2bf(v.x - bf2f(h0)), f2bf(v.y - bf2f(h1)),
                            f2bf(v.z - bf2f(h2)), f2bf(v.w - bf2f(h3)));
  *(ushort4*)(xh + i) = hv;
  *(ushort4*)(xl + i) = lv;
}

// ---------------------------------------------------------------------------
// conv_w: W (fp32 [1024][3072]) -> whT, wlT (bf16 hi/lo, TRANSPOSED [3072][1024])
// ---------------------------------------------------------------------------
__global__ __launch_bounds__(256) void conv_w(const float* __restrict__ W,
                                              unsigned short* __restrict__ wh,
                                              unsigned short* __restrict__ wl) {
  __shared__ unsigned short Th[64][72];
  __shared__ unsigned short Tl[64][72];
  const int t = threadIdx.x;
  const int n0 = blockIdx.x * 64;
  const int k0 = blockIdx.y * 64;
#pragma unroll
  for (int i = 0; i < 4; ++i) {
    int row = i * 16 + (t >> 4);
    int col = (t & 15) * 4;
    float4 v = *(const float4*)(W + (size_t)(k0 + row) * 3072 + n0 + col);
    unsigned short h;
    h = f2bf(v.x); Th[row][col + 0] = h; Tl[row][col + 0] = f2bf(v.x - bf2f(h));
    h = f2bf(v.y); Th[row][col + 1] = h; Tl[row][col + 1] = f2bf(v.y - bf2f(h));
    h = f2bf(v.z); Th[row][col + 2] = h; Tl[row][col + 2] = f2bf(v.z - bf2f(h));
    h = f2bf(v.w); Th[row][col + 3] = h; Tl[row][col + 3] = f2bf(v.w - bf2f(h));
  }
  __syncthreads();
  const int rn = t & 63, qq = t >> 6;
  unsigned int hw[8], lw[8];
#pragma unroll
  for (int j = 0; j < 8; ++j) {
    unsigned short a = Th[qq * 16 + 2 * j][rn], b = Th[qq * 16 + 2 * j + 1][rn];
    hw[j] = (unsigned int)a | ((unsigned int)b << 16);
    unsigned short c = Tl[qq * 16 + 2 * j][rn], d = Tl[qq * 16 + 2 * j + 1][rn];
    lw[j] = (unsigned int)c | ((unsigned int)d << 16);
  }
  size_t o = (size_t)(n0 + rn) * 1024 + k0 + qq * 16;
  *(uint4*)(wh + o)     = make_uint4(hw[0], hw[1], hw[2], hw[3]);
  *(uint4*)(wh + o + 8) = make_uint4(hw[4], hw[5], hw[6], hw[7]);
  *(uint4*)(wl + o)     = make_uint4(lw[0], lw[1], lw[2], lw[3]);
  *(uint4*)(wl + o + 8) = make_uint4(lw[4], lw[5], lw[6], lw[7]);
}

// ---------------------------------------------------------------------------
// K1: qkv = x @ Wqkv via bf16 hi/lo split MFMA (3 passes: hh, hl, lh).
// Epilogue emits: q fp32 (for fg), qr=q+rrb bf16 hi/lo; k fp32 + bf16 hi/lo;
// v TRANSPOSED bf16 hi/lo [b][h][d][l] (for PV B-fragments).
// ---------------------------------------------------------------------------
__global__ __launch_bounds__(256, 2) void qkv_mfma(const unsigned short* __restrict__ xh,
                                                   const unsigned short* __restrict__ xl,
                                                   const unsigned short* __restrict__ wh,
                                                   const unsigned short* __restrict__ wl,
                                                   const float* __restrict__ rrb,
                                                   float* __restrict__ qarr,
                                                   float* __restrict__ karr,
                                                   unsigned short* __restrict__ qrh,
                                                   unsigned short* __restrict__ qrl,
                                                   unsigned short* __restrict__ kharr,
                                                   unsigned short* __restrict__ klarr,
                                                   unsigned short* __restrict__ vTh,
                                                   unsigned short* __restrict__ vTl) {
  __shared__ alignas(16) unsigned short Ah[128 * 32];
  __shared__ alignas(16) unsigned short Al[128 * 32];
  __shared__ alignas(16) unsigned short Bh[128 * 32];
  __shared__ alignas(16) unsigned short Bl[128 * 32];
  const int t = threadIdx.x;
  const int lane = t & 63;
  const int w = t >> 6;
  const int m0 = blockIdx.y * 128;
  const int n0 = blockIdx.x * 128;
  const int wr = w >> 1, wc = w & 1;
  const int l16 = lane & 15, s = lane >> 4;

  const unsigned short* gsrc = (w == 0) ? xh : (w == 1) ? xl : (w == 2) ? wh : wl;
  unsigned short* lbase = (w == 0) ? Ah : (w == 1) ? Al : (w == 2) ? Bh : Bl;
  const int rbase = (w < 2) ? m0 : n0;
  const int srow = lane >> 2, sc = lane & 3;

  int aoff[4], boff[4];
#pragma unroll
  for (int f = 0; f < 4; ++f) {
    int Rm = wr * 64 + f * 16 + l16;
    aoff[f] = Rm * 64 + ((s ^ ((Rm >> 1) & 3)) << 4);
    int Rn = wc * 64 + f * 16 + l16;
    boff[f] = Rn * 64 + ((s ^ ((Rn >> 1) & 3)) << 4);
  }

  f32x4 acc[4][4];
#pragma unroll
  for (int i = 0; i < 4; ++i)
#pragma unroll
    for (int j = 0; j < 4; ++j) acc[i][j] = (f32x4){0.f, 0.f, 0.f, 0.f};

  const char* Ahc = (const char*)Ah;
  const char* Alc = (const char*)Al;
  const char* Bhc = (const char*)Bh;
  const char* Blc = (const char*)Bl;

  for (int k0 = 0; k0 < 1024; k0 += 32) {
#pragma unroll
    for (int u = 0; u < 8; ++u) {
      int row = u * 16 + srow;
      int chunk = sc ^ ((row >> 1) & 3);
      gload_lds16(gsrc + (size_t)(rbase + row) * 1024 + k0 + chunk * 8,
                  lbase + u * 512);
    }
    __syncthreads();

    bf16x8 a_h[4], a_l[4], b_h[4], b_l[4];
#pragma unroll
    for (int f = 0; f < 4; ++f) {
      a_h[f] = *(const bf16x8*)(Ahc + aoff[f]);
      b_h[f] = *(const bf16x8*)(Bhc + boff[f]);
    }
#pragma unroll
    for (int i = 0; i < 4; ++i)
#pragma unroll
      for (int j = 0; j < 4; ++j)
        acc[i][j] = __builtin_amdgcn_mfma_f32_16x16x32_bf16(a_h[i], b_h[j], acc[i][j], 0, 0, 0);
#pragma unroll
    for (int f = 0; f < 4; ++f) b_l[f] = *(const bf16x8*)(Blc + boff[f]);
#pragma unroll
    for (int i = 0; i < 4; ++i)
#pragma unroll
      for (int j = 0; j < 4; ++j)
        acc[i][j] = __builtin_amdgcn_mfma_f32_16x16x32_bf16(a_h[i], b_l[j], acc[i][j], 0, 0, 0);
#pragma unroll
    for (int f = 0; f < 4; ++f) a_l[f] = *(const bf16x8*)(Alc + aoff[f]);
#pragma unroll
    for (int i = 0; i < 4; ++i)
#pragma unroll
      for (int j = 0; j < 4; ++j)
        acc[i][j] = __builtin_amdgcn_mfma_f32_16x16x32_bf16(a_l[i], b_h[j], acc[i][j], 0, 0, 0);
    __syncthreads();
  }

  // epilogue: C/D layout col=lane&15, row=(lane>>4)*4+reg
  const int part = n0 >> 10;
  const int nb = n0 & 1023;
#pragma unroll
  for (int i = 0; i < 4; ++i) {
#pragma unroll
    for (int j = 0; j < 4; ++j) {
      const int n = nb + wc * 64 + j * 16 + l16;
      const int h = n >> 6, d = n & 63;
      const int mb = m0 + wr * 64 + i * 16 + (lane >> 4) * 4;
      const int bb = mb >> 9, lb = mb & 511;  // 4 consecutive l, same bb
      const size_t rowbase = ((size_t)(bb * Hn + h) * Ln + lb) << 6;
      if (part == 0) {
        const float rr = rrb[h * HD + d];
#pragma unroll
        for (int r = 0; r < 4; ++r) {
          const float v = acc[i][j][r];
          const size_t qi = rowbase + ((size_t)r << 6) + d;
          qarr[qi] = v;
          const float qv = v + rr;
          const unsigned short hh = f2bf(qv);
          qrh[qi] = hh;
          qrl[qi] = f2bf(qv - bf2f(hh));
        }
      } else if (part == 1) {
#pragma unroll
        for (int r = 0; r < 4; ++r) {
          const float v = acc[i][j][r];
          const size_t qi = rowbase + ((size_t)r << 6) + d;
          karr[qi] = v;
          const unsigned short hh = f2bf(v);
          kharr[qi] = hh;
          klarr[qi] = f2bf(v - bf2f(hh));
        }
      } else {
        // v transposed: [b][h][d][l], 4 consecutive l -> pack ushort4
        ushort4 hv, lv;
        unsigned short* hp = &hv.x;
        unsigned short* lp = &lv.x;
#pragma unroll
        for (int r = 0; r < 4; ++r) {
          const float v = acc[i][j][r];
          const unsigned short hh = f2bf(v);
          hp[r] = hh;
          lp[r] = f2bf(v - bf2f(hh));
        }
        const size_t vi = ((size_t)(bb * Hn + h) * HD + d) * Ln + lb;
        *(ushort4*)(vTh + vi) = hv;
        *(ushort4*)(vTl + vi) = lv;
      }
    }
  }
}

// ---------------------------------------------------------------------------
// K2 (per batch): banded, pre-shifted F/G (unchanged from prior round).
// ---------------------------------------------------------------------------
__global__ __launch_bounds__(256) void fg_gemm(const float* __restrict__ qarr,
                                               const float* __restrict__ karr,
                                               const float* __restrict__ rwb,
                                               const float* __restrict__ R,
                                               float* __restrict__ Fs,
                                               float* __restrict__ Gs,
                                               int b) {
  const int m0 = blockIdx.y * 64;
  const int n0 = blockIdx.x * 64;
  if (m0 + n0 + 126 < 512 || m0 + n0 >= 1024) return;

  __shared__ float As[64][68];
  __shared__ float Rs[64][68];
  const int t = threadIdx.x;
  const int h = blockIdx.z >> 1;
  const int which = blockIdx.z & 1;
  const float* A = (which == 0 ? qarr : karr) + (size_t)(b * Hn + h) * Ln * HD;

#pragma unroll
  for (int i = 0; i < 4; ++i) {
    int idx = t + i * 256;
    int r = idx >> 4;
    int c4 = (idx & 15) * 4;
    float4 av = *(const float4*)(A + (size_t)(m0 + r) * HD + c4);
    if (which == 0) {
      float4 bv = *(const float4*)(rwb + h * HD + c4);
      av.x += bv.x; av.y += bv.y; av.z += bv.z; av.w += bv.w;
    }
    As[c4 + 0][r] = av.x; As[c4 + 1][r] = av.y;
    As[c4 + 2][r] = av.z; As[c4 + 3][r] = av.w;
    *(float4*)(&Rs[r][c4]) = *(const float4*)(R + (size_t)r * TL + n0 + c4);
  }
  __syncthreads();
  const int tr = t >> 4, tc = t & 15;
  float acc[4][4];
#pragma unroll
  for (int i = 0; i < 4; ++i)
#pragma unroll
    for (int j = 0; j < 4; ++j) acc[i][j] = 0.f;
#pragma unroll 16
  for (int kk = 0; kk < 64; ++kk) {
    float a[4], bb[4];
    *(float4*)(a)  = *(const float4*)(&As[kk][tr * 4]);
    *(float4*)(bb) = *(const float4*)(&Rs[kk][tc * 4]);
#pragma unroll
    for (int i = 0; i < 4; ++i)
#pragma unroll
      for (int j = 0; j < 4; ++j) acc[i][j] = fmaf(a[i], bb[j], acc[i][j]);
  }
  if (which == 0) {
    float* O = Fs + (size_t)h * Ln * Ln;
#pragma unroll
    for (int i = 0; i < 4; ++i) {
      const int q = m0 + tr * 4 + i;
#pragma unroll
      for (int jj = 0; jj < 4; ++jj) {
        const int p = n0 + tc * 4 + jj;
        const int j = p + q - 512;
        if ((unsigned)j < 512u) O[((size_t)q << 9) + j] = acc[i][jj];
      }
    }
  } else {
    float* O = Gs + (size_t)h * Ln * Ln;
#pragma unroll
    for (int i = 0; i < 4; ++i) {
      const int jrow = m0 + tr * 4 + i;
#pragma unroll
      for (int jj = 0; jj < 4; ++jj) {
        const int p = n0 + tc * 4 + jj;
        const int q = p + jrow - 512;
        if ((unsigned)q < 512u) O[((size_t)q << 9) + jrow] = acc[i][jj];
      }
    }
  }
}

// ---------------------------------------------------------------------------
// K3 (per batch): MFMA flash attention. One wave (64 threads) owns 16 q-rows
// of one (b,h); iterates 8 j-tiles of 64. Zero __syncthreads.
//   S = qr@k^T (bf16 hi/lo, 3 passes) -> +Fs+Gs, /8, +prev -> pout
//   in-register online softmax (shfl over 16-lane column groups)
//   P -> bf16 hi/lo -> private LDS (chunk-XOR swizzle) -> PV MFMA (3 passes)
// ---------------------------------------------------------------------------
__global__ __launch_bounds__(64) void attn_mfma(const unsigned short* __restrict__ qrh,
                                                const unsigned short* __restrict__ qrl,
                                                const unsigned short* __restrict__ kharr,
                                                const unsigned short* __restrict__ klarr,
                                                const unsigned short* __restrict__ vTh,
                                                const unsigned short* __restrict__ vTl,
                                                const float* __restrict__ Fs,
                                                const float* __restrict__ Gs,
                                                const float* __restrict__ prev,
                                                const int* __restrict__ skip,
                                                float* __restrict__ out,
                                                float* __restrict__ pout,
                                                int b) {
  __shared__ alignas(16) unsigned short PhL[16 * 64];
  __shared__ alignas(16) unsigned short PlL[16 * 64];
  const int lane = threadIdx.x & 63;
  const int s = lane >> 4, l16 = lane & 15;
  const int h = blockIdx.y;
  const int q0 = blockIdx.x * 16;  // wave's q base
  const size_t bh = (size_t)(b * Hn + h);
  const float pf = (skip[0] != 0) ? 1.f : 0.f;

  // A-fragments of qr (constant over all j-tiles): row=l16, k=kd*32+s*8
  bf16x8 aqh[2], aql[2];
#pragma unroll
  for (int kd = 0; kd < 2; ++kd) {
    const size_t a = ((bh * Ln + q0 + l16) << 6) + kd * 32 + s * 8;
    aqh[kd] = *(const bf16x8*)(qrh + a);
    aql[kd] = *(const bf16x8*)(qrl + a);
  }

  float m_run[4] = {-INFINITY, -INFINITY, -INFINITY, -INFINITY};
  float l_run[4] = {0.f, 0.f, 0.f, 0.f};
  f32x4 O[4];
#pragma unroll
  for (int fo = 0; fo < 4; ++fo) O[fo] = (f32x4){0.f, 0.f, 0.f, 0.f};

  const int qrow = q0 + s * 4;  // D-frag rows: qrow + r

  for (int jt = 0; jt < 8; ++jt) {
    const int j0 = jt * 64;

    // ---- S = qr @ k^T ----
    f32x4 S[4];
#pragma unroll
    for (int fi = 0; fi < 4; ++fi) S[fi] = (f32x4){0.f, 0.f, 0.f, 0.f};
#pragma unroll
    for (int kd = 0; kd < 2; ++kd) {
#pragma unroll
      for (int fi = 0; fi < 4; ++fi) {
        const size_t ka = ((bh * Ln + j0 + fi * 16 + l16) << 6) + kd * 32 + s * 8;
        const bf16x8 bkh = *(const bf16x8*)(kharr + ka);
        const bf16x8 bkl = *(const bf16x8*)(klarr + ka);
        S[fi] = __builtin_amdgcn_mfma_f32_16x16x32_bf16(aqh[kd], bkh, S[fi], 0, 0, 0);
        S[fi] = __builtin_amdgcn_mfma_f32_16x16x32_bf16(aqh[kd], bkl, S[fi], 0, 0, 0);
        S[fi] = __builtin_amdgcn_mfma_f32_16x16x32_bf16(aql[kd], bkh, S[fi], 0, 0, 0);
      }
    }

    // ---- combine with Fs/Gs/prev, write pout ----
    float sc[4][4];
    float mx[4] = {-INFINITY, -INFINITY, -INFINITY, -INFINITY};
#pragma unroll
    for (int fi = 0; fi < 4; ++fi) {
      const int j = j0 + fi * 16 + l16;
#pragma unroll
      for (int r = 0; r < 4; ++r) {
        const int q = qrow + r;
        const size_t fb = (((size_t)h * Ln + q) << 9) + j;
        const size_t pb = ((bh * Ln + q) << 9) + j;
        const float v = (S[fi][r] + Fs[fb] + Gs[fb]) * 0.125f + pf * prev[pb];
        pout[pb] = v;
        sc[fi][r] = v;
        mx[r] = fmaxf(mx[r], v);
      }
    }

    // ---- online softmax (row reduce over 16-lane column group) ----
    float al[4];
#pragma unroll
    for (int r = 0; r < 4; ++r) {
      float m = mx[r];
      m = fmaxf(m, __shfl_xor(m, 1));
      m = fmaxf(m, __shfl_xor(m, 2));
      m = fmaxf(m, __shfl_xor(m, 4));
      m = fmaxf(m, __shfl_xor(m, 8));
      const float mn = fmaxf(m_run[r], m);
      al[r] = __expf(m_run[r] - mn);
      m_run[r] = mn;
    }

    // ---- P = exp(S - m), bf16 hi/lo -> LDS, row sums ----
    float sum[4] = {0.f, 0.f, 0.f, 0.f};
#pragma unroll
    for (int fi = 0; fi < 4; ++fi) {
      const int jloc = fi * 16 + l16;
      const int chunk = jloc >> 3, sub = jloc & 7;
#pragma unroll
      for (int r = 0; r < 4; ++r) {
        const float p = __expf(sc[fi][r] - m_run[r]);
        sum[r] += p;
        const unsigned short ph = f2bf(p);
        const unsigned short pl = f2bf(p - bf2f(ph));
        const int qloc = s * 4 + r;
        const int idx = (qloc << 6) + ((chunk ^ (qloc & 7)) << 3) + sub;
        PhL[idx] = ph;
        PlL[idx] = pl;
      }
    }
#pragma unroll
    for (int r = 0; r < 4; ++r) {
      float sm = sum[r];
      sm += __shfl_xor(sm, 1);
      sm += __shfl_xor(sm, 2);
      sm += __shfl_xor(sm, 4);
      sm += __shfl_xor(sm, 8);
      l_run[r] = l_run[r] * al[r] + sm;
    }

    // ---- O rescale + PV ----
#pragma unroll
    for (int fo = 0; fo < 4; ++fo)
#pragma unroll
      for (int r = 0; r < 4; ++r) O[fo][r] *= al[r];

#pragma unroll
    for (int kj = 0; kj < 2; ++kj) {
      const int raddr = (l16 << 6) + (((kj * 4 + s) ^ (l16 & 7)) << 3);
      const bf16x8 pah = *(const bf16x8*)(PhL + raddr);
      const bf16x8 pal = *(const bf16x8*)(PlL + raddr);
#pragma unroll
      for (int fo = 0; fo < 4; ++fo) {
        const size_t va = ((bh << 6) + fo * 16 + l16) * (size_t)Ln + j0 + kj * 32 + s * 8;
        const bf16x8 vbh = *(const bf16x8*)(vTh + va);
        const bf16x8 vbl = *(const bf16x8*)(vTl + va);
        O[fo] = __builtin_amdgcn_mfma_f32_16x16x32_bf16(pah, vbh, O[fo], 0, 0, 0);
        O[fo] = __builtin_amdgcn_mfma_f32_16x16x32_bf16(pah, vbl, O[fo], 0, 0, 0);
        O[fo] = __builtin_amdgcn_mfma_f32_16x16x32_bf16(pal, vbh, O[fo], 0, 0, 0);
      }
    }
  }

  // ---- epilogue: out = O / l ----
#pragma unroll
  for (int r = 0; r < 4; ++r) {
    const float inv = 1.0f / l_run[r];
    const size_t ob = ((size_t)b * Ln + qrow + r) * DM + h * HD;
#pragma unroll
    for (int fo = 0; fo < 4; ++fo) {
      out[ob + fo * 16 + l16] = O[fo][r] * inv;
    }
  }
}

// ---------------------------------------------------------------------------
// kernel_launch
// ws layout: qarr(f32,QS) | karr(f32,QS) | qrh qrl kh kl vTh vTl (bf16, QS ea)
//            | Fs(f32,FSz) | Gs(f32,FSz)   = 7*QS floats = 117.4 MB
// bf16 staging (xh|xl|wh|wl, 29.5 MB) aliases Fs/Gs (33.6 MB): consumed by
// qkv_mfma before fg_gemm first writes Fs/Gs.
// ---------------------------------------------------------------------------
extern "C" void kernel_launch(void* const* d_in, const int* in_sizes, int n_in,
                              void* d_out, int out_size, void* d_ws, size_t ws_size,
                              hipStream_t stream) {
  const float* x    = (const float*)d_in[0];
  const float* prev = (const float*)d_in[1];
  const float* W    = (const float*)d_in[2];
  const float* rrb  = (const float*)d_in[3];
  const float* rwb  = (const float*)d_in[4];
  const float* R    = (const float*)d_in[5];
  const int*   skip = (const int*)d_in[6];

  float* out  = (float*)d_out;
  float* pout = out + (size_t)Bn * Ln * DM;

  float* ws = (float*)d_ws;
  float* qarr = ws;
  float* karr = ws + QS;
  unsigned short* qrh = (unsigned short*)(ws + 2 * QS);
  unsigned short* qrl = qrh + QS;
  unsigned short* kh  = qrl + QS;
  unsigned short* kl  = kh + QS;
  unsigned short* vTh = kl + QS;
  unsigned short* vTl = vTh + QS;
  float* Farr = ws + 5 * QS;
  float* Garr = Farr + FSz;

  unsigned short* xh = (unsigned short*)Farr;  // staging aliases Fs/Gs region
  unsigned short* xl = xh + QS;
  unsigned short* wwh = xl + QS;
  unsigned short* wwl = wwh + WN;

  conv_x<<<dim3(4096), 256, 0, stream>>>(x, xh, xl);
  conv_w<<<dim3(48, 16), 256, 0, stream>>>(W, wwh, wwl);
  qkv_mfma<<<dim3(24, 32), 256, 0, stream>>>(xh, xl, wwh, wwl, rrb, qarr, karr,
                                             qrh, qrl, kh, kl, vTh, vTl);
  for (int b = 0; b < Bn; ++b) {
    fg_gemm<<<dim3(TL / 64, Ln / 64, Hn * 2), 256, 0, stream>>>(qarr, karr, rwb, R, Farr, Garr, b);
    attn_mfma<<<dim3(Ln / 16, Hn), 64, 0, stream>>>(qrh, qrl, kh, kl, vTh, vTl,
                                                    Farr, Garr, prev, skip, out, pout, b);
  }
}

// Round 4
// 977.478 us; speedup vs baseline: 1.1437x; 1.1437x over previous
//
#include <hip/hip_runtime.h>
#include <hip/hip_bf16.h>
#include <math.h>

// Problem constants
namespace {
constexpr int Bn = 8;
constexpr int Hn = 16;
constexpr int Ln = 512;
constexpr int HD = 64;
constexpr int DM = 1024;
constexpr int TL = 1024;  // 2*L
constexpr size_t QS  = (size_t)Bn * Hn * Ln * HD;  // 4,194,304 elems per q/k/v-sized array
constexpr size_t FSz = (size_t)Hn * Ln * Ln;       // 4,194,304 floats per-batch Fs (or Gs), banded
constexpr size_t WN  = (size_t)DM * 3 * DM;        // 3,145,728 W elements
}

typedef __bf16 bf16x8 __attribute__((ext_vector_type(8)));
typedef float f32x4 __attribute__((ext_vector_type(4)));

typedef __attribute__((address_space(1))) void as1_void_t;
typedef __attribute__((address_space(3))) void as3_void_t;

__device__ __forceinline__ void gload_lds16(const void* g, void* l) {
  __builtin_amdgcn_global_load_lds((as1_void_t*)g, (as3_void_t*)l, 16, 0, 0);
}

__device__ __forceinline__ unsigned short f2bf(float f) {
  unsigned int u = __float_as_uint(f);
  u += 0x7fffu + ((u >> 16) & 1u);  // round-to-nearest-even
  return (unsigned short)(u >> 16);
}
__device__ __forceinline__ float bf2f(unsigned short h) {
  return __uint_as_float(((unsigned int)h) << 16);
}

// ---------------------------------------------------------------------------
// conv_x: x (fp32 [4096][1024]) -> xh, xl (bf16 hi/lo, same layout)
// ---------------------------------------------------------------------------
__global__ __launch_bounds__(256) void conv_x(const float* __restrict__ x,
                                              unsigned short* __restrict__ xh,
                                              unsigned short* __restrict__ xl) {
  size_t i = ((size_t)blockIdx.x * 256 + threadIdx.x) * 4;
  float4 v = *(const float4*)(x + i);
  unsigned short h0 = f2bf(v.x), h1 = f2bf(v.y), h2 = f2bf(v.z), h3 = f2bf(v.w);
  ushort4 hv = make_ushort4(h0, h1, h2, h3);
  ushort4 lv = make_ushort4(f2bf(v.x - bf2f(h0)), f2bf(v.y - bf2f(h1)),
                            f2bf(v.z - bf2f(h2)), f2bf(v.w - bf2f(h3)));
  *(ushort4*)(xh + i) = hv;
  *(ushort4*)(xl + i) = lv;
}

// ---------------------------------------------------------------------------
// conv_w: W (fp32 [1024][3072]) -> whT, wlT (bf16 hi/lo, TRANSPOSED [3072][1024])
// ---------------------------------------------------------------------------
__global__ __launch_bounds__(256) void conv_w(const float* __restrict__ W,
                                              unsigned short* __restrict__ wh,
                                              unsigned short* __restrict__ wl) {
  __shared__ unsigned short Th[64][72];
  __shared__ unsigned short Tl[64][72];
  const int t = threadIdx.x;
  const int n0 = blockIdx.x * 64;
  const int k0 = blockIdx.y * 64;
#pragma unroll
  for (int i = 0; i < 4; ++i) {
    int row = i * 16 + (t >> 4);
    int col = (t & 15) * 4;
    float4 v = *(const float4*)(W + (size_t)(k0 + row) * 3072 + n0 + col);
    unsigned short h;
    h = f2bf(v.x); Th[row][col + 0] = h; Tl[row][col + 0] = f2bf(v.x - bf2f(h));
    h = f2bf(v.y); Th[row][col + 1] = h; Tl[row][col + 1] = f2bf(v.y - bf2f(h));
    h = f2bf(v.z); Th[row][col + 2] = h; Tl[row][col + 2] = f2bf(v.z - bf2f(h));
    h = f2bf(v.w); Th[row][col + 3] = h; Tl[row][col + 3] = f2bf(v.w - bf2f(h));
  }
  __syncthreads();
  const int rn = t & 63, qq = t >> 6;
  unsigned int hw[8], lw[8];
#pragma unroll
  for (int j = 0; j < 8; ++j) {
    unsigned short a = Th[qq * 16 + 2 * j][rn], b = Th[qq * 16 + 2 * j + 1][rn];
    hw[j] = (unsigned int)a | ((unsigned int)b << 16);
    unsigned short c = Tl[qq * 16 + 2 * j][rn], d = Tl[qq * 16 + 2 * j + 1][rn];
    lw[j] = (unsigned int)c | ((unsigned int)d << 16);
  }
  size_t o = (size_t)(n0 + rn) * 1024 + k0 + qq * 16;
  *(uint4*)(wh + o)     = make_uint4(hw[0], hw[1], hw[2], hw[3]);
  *(uint4*)(wh + o + 8) = make_uint4(hw[4], hw[5], hw[6], hw[7]);
  *(uint4*)(wl + o)     = make_uint4(lw[0], lw[1], lw[2], lw[3]);
  *(uint4*)(wl + o + 8) = make_uint4(lw[4], lw[5], lw[6], lw[7]);
}

// ---------------------------------------------------------------------------
// K1: qkv = x @ Wqkv via bf16 hi/lo split MFMA (3 passes: hh, hl, lh).
// Epilogue emits ONLY bf16 hi/lo: qr=q+rrb; k; v TRANSPOSED [b][h][d][l].
// fg_gemm reconstructs fp32 from hi+lo (error ~2^-16).
// ---------------------------------------------------------------------------
__global__ __launch_bounds__(256, 2) void qkv_mfma(const unsigned short* __restrict__ xh,
                                                   const unsigned short* __restrict__ xl,
                                                   const unsigned short* __restrict__ wh,
                                                   const unsigned short* __restrict__ wl,
                                                   const float* __restrict__ rrb,
                                                   unsigned short* __restrict__ qrh,
                                                   unsigned short* __restrict__ qrl,
                                                   unsigned short* __restrict__ kharr,
                                                   unsigned short* __restrict__ klarr,
                                                   unsigned short* __restrict__ vTh,
                                                   unsigned short* __restrict__ vTl) {
  __shared__ alignas(16) unsigned short Ah[128 * 32];
  __shared__ alignas(16) unsigned short Al[128 * 32];
  __shared__ alignas(16) unsigned short Bh[128 * 32];
  __shared__ alignas(16) unsigned short Bl[128 * 32];
  const int t = threadIdx.x;
  const int lane = t & 63;
  const int w = t >> 6;
  const int m0 = blockIdx.y * 128;
  const int n0 = blockIdx.x * 128;
  const int wr = w >> 1, wc = w & 1;
  const int l16 = lane & 15, s = lane >> 4;

  const unsigned short* gsrc = (w == 0) ? xh : (w == 1) ? xl : (w == 2) ? wh : wl;
  unsigned short* lbase = (w == 0) ? Ah : (w == 1) ? Al : (w == 2) ? Bh : Bl;
  const int rbase = (w < 2) ? m0 : n0;
  const int srow = lane >> 2, sc = lane & 3;

  int aoff[4], boff[4];
#pragma unroll
  for (int f = 0; f < 4; ++f) {
    int Rm = wr * 64 + f * 16 + l16;
    aoff[f] = Rm * 64 + ((s ^ ((Rm >> 1) & 3)) << 4);
    int Rn = wc * 64 + f * 16 + l16;
    boff[f] = Rn * 64 + ((s ^ ((Rn >> 1) & 3)) << 4);
  }

  f32x4 acc[4][4];
#pragma unroll
  for (int i = 0; i < 4; ++i)
#pragma unroll
    for (int j = 0; j < 4; ++j) acc[i][j] = (f32x4){0.f, 0.f, 0.f, 0.f};

  const char* Ahc = (const char*)Ah;
  const char* Alc = (const char*)Al;
  const char* Bhc = (const char*)Bh;
  const char* Blc = (const char*)Bl;

  for (int k0 = 0; k0 < 1024; k0 += 32) {
#pragma unroll
    for (int u = 0; u < 8; ++u) {
      int row = u * 16 + srow;
      int chunk = sc ^ ((row >> 1) & 3);
      gload_lds16(gsrc + (size_t)(rbase + row) * 1024 + k0 + chunk * 8,
                  lbase + u * 512);
    }
    __syncthreads();

    bf16x8 a_h[4], a_l[4], b_h[4], b_l[4];
#pragma unroll
    for (int f = 0; f < 4; ++f) {
      a_h[f] = *(const bf16x8*)(Ahc + aoff[f]);
      b_h[f] = *(const bf16x8*)(Bhc + boff[f]);
    }
#pragma unroll
    for (int i = 0; i < 4; ++i)
#pragma unroll
      for (int j = 0; j < 4; ++j)
        acc[i][j] = __builtin_amdgcn_mfma_f32_16x16x32_bf16(a_h[i], b_h[j], acc[i][j], 0, 0, 0);
#pragma unroll
    for (int f = 0; f < 4; ++f) b_l[f] = *(const bf16x8*)(Blc + boff[f]);
#pragma unroll
    for (int i = 0; i < 4; ++i)
#pragma unroll
      for (int j = 0; j < 4; ++j)
        acc[i][j] = __builtin_amdgcn_mfma_f32_16x16x32_bf16(a_h[i], b_l[j], acc[i][j], 0, 0, 0);
#pragma unroll
    for (int f = 0; f < 4; ++f) a_l[f] = *(const bf16x8*)(Alc + aoff[f]);
#pragma unroll
    for (int i = 0; i < 4; ++i)
#pragma unroll
      for (int j = 0; j < 4; ++j)
        acc[i][j] = __builtin_amdgcn_mfma_f32_16x16x32_bf16(a_l[i], b_h[j], acc[i][j], 0, 0, 0);
    __syncthreads();
  }

  // epilogue: C/D layout col=lane&15, row=(lane>>4)*4+reg
  const int part = n0 >> 10;
  const int nb = n0 & 1023;
#pragma unroll
  for (int i = 0; i < 4; ++i) {
#pragma unroll
    for (int j = 0; j < 4; ++j) {
      const int n = nb + wc * 64 + j * 16 + l16;
      const int h = n >> 6, d = n & 63;
      const int mb = m0 + wr * 64 + i * 16 + (lane >> 4) * 4;
      const int bb = mb >> 9, lb = mb & 511;  // 4 consecutive l, same bb
      const size_t rowbase = ((size_t)(bb * Hn + h) * Ln + lb) << 6;
      if (part == 0) {
        const float rr = rrb[h * HD + d];
#pragma unroll
        for (int r = 0; r < 4; ++r) {
          const float qv = acc[i][j][r] + rr;
          const size_t qi = rowbase + ((size_t)r << 6) + d;
          const unsigned short hh = f2bf(qv);
          qrh[qi] = hh;
          qrl[qi] = f2bf(qv - bf2f(hh));
        }
      } else if (part == 1) {
#pragma unroll
        for (int r = 0; r < 4; ++r) {
          const float v = acc[i][j][r];
          const size_t qi = rowbase + ((size_t)r << 6) + d;
          const unsigned short hh = f2bf(v);
          kharr[qi] = hh;
          klarr[qi] = f2bf(v - bf2f(hh));
        }
      } else {
        // v transposed: [b][h][d][l], 4 consecutive l -> pack ushort4
        ushort4 hv, lv;
        unsigned short* hp = &hv.x;
        unsigned short* lp = &lv.x;
#pragma unroll
        for (int r = 0; r < 4; ++r) {
          const float v = acc[i][j][r];
          const unsigned short hh = f2bf(v);
          hp[r] = hh;
          lp[r] = f2bf(v - bf2f(hh));
        }
        const size_t vi = ((size_t)(bb * Hn + h) * HD + d) * Ln + lb;
        *(ushort4*)(vTh + vi) = hv;
        *(ushort4*)(vTl + vi) = lv;
      }
    }
  }
}

// ---------------------------------------------------------------------------
// K2 (per batch): banded, pre-shifted F/G. A operands reconstructed from
// bf16 hi/lo: q = (qrh+qrl) - rrb + rwb ; k = kh+kl.
// ---------------------------------------------------------------------------
__global__ __launch_bounds__(256) void fg_gemm(const unsigned short* __restrict__ qrh,
                                               const unsigned short* __restrict__ qrl,
                                               const unsigned short* __restrict__ kharr,
                                               const unsigned short* __restrict__ klarr,
                                               const float* __restrict__ rrb,
                                               const float* __restrict__ rwb,
                                               const float* __restrict__ R,
                                               float* __restrict__ Fs,
                                               float* __restrict__ Gs,
                                               int b) {
  const int m0 = blockIdx.y * 64;
  const int n0 = blockIdx.x * 64;
  if (m0 + n0 + 126 < 512 || m0 + n0 >= 1024) return;

  __shared__ float As[64][68];
  __shared__ float Rs[64][68];
  const int t = threadIdx.x;
  const int h = blockIdx.z >> 1;
  const int which = blockIdx.z & 1;
  const size_t abase = (size_t)(b * Hn + h) * Ln * HD;
  const unsigned short* Ahp = (which == 0 ? qrh : kharr) + abase;
  const unsigned short* Alp = (which == 0 ? qrl : klarr) + abase;

#pragma unroll
  for (int i = 0; i < 4; ++i) {
    int idx = t + i * 256;
    int r = idx >> 4;
    int c4 = (idx & 15) * 4;
    ushort4 h4 = *(const ushort4*)(Ahp + (size_t)(m0 + r) * HD + c4);
    ushort4 l4 = *(const ushort4*)(Alp + (size_t)(m0 + r) * HD + c4);
    float vx = bf2f(h4.x) + bf2f(l4.x);
    float vy = bf2f(h4.y) + bf2f(l4.y);
    float vz = bf2f(h4.z) + bf2f(l4.z);
    float vw = bf2f(h4.w) + bf2f(l4.w);
    if (which == 0) {
      float4 rr = *(const float4*)(rrb + h * HD + c4);
      float4 rw = *(const float4*)(rwb + h * HD + c4);
      vx += rw.x - rr.x; vy += rw.y - rr.y;
      vz += rw.z - rr.z; vw += rw.w - rr.w;
    }
    As[c4 + 0][r] = vx; As[c4 + 1][r] = vy;
    As[c4 + 2][r] = vz; As[c4 + 3][r] = vw;
    *(float4*)(&Rs[r][c4]) = *(const float4*)(R + (size_t)r * TL + n0 + c4);
  }
  __syncthreads();
  const int tr = t >> 4, tc = t & 15;
  float acc[4][4];
#pragma unroll
  for (int i = 0; i < 4; ++i)
#pragma unroll
    for (int j = 0; j < 4; ++j) acc[i][j] = 0.f;
#pragma unroll 16
  for (int kk = 0; kk < 64; ++kk) {
    float a[4], bb[4];
    *(float4*)(a)  = *(const float4*)(&As[kk][tr * 4]);
    *(float4*)(bb) = *(const float4*)(&Rs[kk][tc * 4]);
#pragma unroll
    for (int i = 0; i < 4; ++i)
#pragma unroll
      for (int j = 0; j < 4; ++j) acc[i][j] = fmaf(a[i], bb[j], acc[i][j]);
  }
  if (which == 0) {
    float* O = Fs + (size_t)h * Ln * Ln;
#pragma unroll
    for (int i = 0; i < 4; ++i) {
      const int q = m0 + tr * 4 + i;
#pragma unroll
      for (int jj = 0; jj < 4; ++jj) {
        const int p = n0 + tc * 4 + jj;
        const int j = p + q - 512;
        if ((unsigned)j < 512u) O[((size_t)q << 9) + j] = acc[i][jj];
      }
    }
  } else {
    float* O = Gs + (size_t)h * Ln * Ln;
#pragma unroll
    for (int i = 0; i < 4; ++i) {
      const int jrow = m0 + tr * 4 + i;
#pragma unroll
      for (int jj = 0; jj < 4; ++jj) {
        const int p = n0 + tc * 4 + jj;
        const int q = p + jrow - 512;
        if ((unsigned)q < 512u) O[((size_t)q << 9) + jrow] = acc[i][jj];
      }
    }
  }
}

// ---------------------------------------------------------------------------
// K3 (per batch): MFMA flash attention, j-split across 4 waves + flash merge.
// Block = 256 threads (4 waves) owns 16 q-rows of one (b,h). Wave w handles
// j-tiles {2w, 2w+1} with private (m,l,O); block-level flash combine via LDS.
// ---------------------------------------------------------------------------
__global__ __launch_bounds__(256) void attn_mfma(const unsigned short* __restrict__ qrh,
                                                 const unsigned short* __restrict__ qrl,
                                                 const unsigned short* __restrict__ kharr,
                                                 const unsigned short* __restrict__ klarr,
                                                 const unsigned short* __restrict__ vTh,
                                                 const unsigned short* __restrict__ vTl,
                                                 const float* __restrict__ Fs,
                                                 const float* __restrict__ Gs,
                                                 const float* __restrict__ prev,
                                                 const int* __restrict__ skip,
                                                 float* __restrict__ out,
                                                 float* __restrict__ pout,
                                                 int b) {
  __shared__ alignas(16) unsigned short PhL[4][16 * 64];
  __shared__ alignas(16) unsigned short PlL[4][16 * 64];
  __shared__ float Om[4][16][65];
  __shared__ float mw[4][16];
  __shared__ float lw[4][16];

  const int t = threadIdx.x;
  const int w = t >> 6;
  const int lane = t & 63;
  const int s = lane >> 4, l16 = lane & 15;
  const int h = blockIdx.y;
  const int q0 = blockIdx.x * 16;
  const size_t bh = (size_t)(b * Hn + h);
  const float pf = (skip[0] != 0) ? 1.f : 0.f;

  // A-fragments of qr (constant over j-tiles): row=l16, k=kd*32+s*8
  bf16x8 aqh[2], aql[2];
#pragma unroll
  for (int kd = 0; kd < 2; ++kd) {
    const size_t a = ((bh * Ln + q0 + l16) << 6) + kd * 32 + s * 8;
    aqh[kd] = *(const bf16x8*)(qrh + a);
    aql[kd] = *(const bf16x8*)(qrl + a);
  }

  float m_run[4] = {-INFINITY, -INFINITY, -INFINITY, -INFINITY};
  float l_run[4] = {0.f, 0.f, 0.f, 0.f};
  f32x4 O[4];
#pragma unroll
  for (int fo = 0; fo < 4; ++fo) O[fo] = (f32x4){0.f, 0.f, 0.f, 0.f};

  const int qrow = q0 + s * 4;
  unsigned short* PhW = &PhL[w][0];
  unsigned short* PlW = &PlL[w][0];

#pragma unroll
  for (int it = 0; it < 2; ++it) {
    const int j0 = (w * 2 + it) * 64;

    // ---- S = qr @ k^T ----
    f32x4 S[4];
#pragma unroll
    for (int fi = 0; fi < 4; ++fi) S[fi] = (f32x4){0.f, 0.f, 0.f, 0.f};
#pragma unroll
    for (int kd = 0; kd < 2; ++kd) {
#pragma unroll
      for (int fi = 0; fi < 4; ++fi) {
        const size_t ka = ((bh * Ln + j0 + fi * 16 + l16) << 6) + kd * 32 + s * 8;
        const bf16x8 bkh = *(const bf16x8*)(kharr + ka);
        const bf16x8 bkl = *(const bf16x8*)(klarr + ka);
        S[fi] = __builtin_amdgcn_mfma_f32_16x16x32_bf16(aqh[kd], bkh, S[fi], 0, 0, 0);
        S[fi] = __builtin_amdgcn_mfma_f32_16x16x32_bf16(aqh[kd], bkl, S[fi], 0, 0, 0);
        S[fi] = __builtin_amdgcn_mfma_f32_16x16x32_bf16(aql[kd], bkh, S[fi], 0, 0, 0);
      }
    }

    // ---- combine with Fs/Gs/prev, write pout ----
    float sc[4][4];
    float mx[4] = {-INFINITY, -INFINITY, -INFINITY, -INFINITY};
#pragma unroll
    for (int fi = 0; fi < 4; ++fi) {
      const int j = j0 + fi * 16 + l16;
#pragma unroll
      for (int r = 0; r < 4; ++r) {
        const int q = qrow + r;
        const size_t fb = (((size_t)h * Ln + q) << 9) + j;
        const size_t pb = ((bh * Ln + q) << 9) + j;
        const float v = (S[fi][r] + Fs[fb] + Gs[fb]) * 0.125f + pf * prev[pb];
        pout[pb] = v;
        sc[fi][r] = v;
        mx[r] = fmaxf(mx[r], v);
      }
    }

    // ---- online softmax (row reduce over 16-lane column group) ----
    float al[4];
#pragma unroll
    for (int r = 0; r < 4; ++r) {
      float m = mx[r];
      m = fmaxf(m, __shfl_xor(m, 1));
      m = fmaxf(m, __shfl_xor(m, 2));
      m = fmaxf(m, __shfl_xor(m, 4));
      m = fmaxf(m, __shfl_xor(m, 8));
      const float mn = fmaxf(m_run[r], m);
      al[r] = __expf(m_run[r] - mn);
      m_run[r] = mn;
    }

    // ---- P = exp(S - m), bf16 hi/lo -> private LDS, row sums ----
    float sum[4] = {0.f, 0.f, 0.f, 0.f};
#pragma unroll
    for (int fi = 0; fi < 4; ++fi) {
      const int jloc = fi * 16 + l16;
      const int chunk = jloc >> 3, sub = jloc & 7;
#pragma unroll
      for (int r = 0; r < 4; ++r) {
        const float p = __expf(sc[fi][r] - m_run[r]);
        sum[r] += p;
        const unsigned short ph = f2bf(p);
        const unsigned short pl = f2bf(p - bf2f(ph));
        const int qloc = s * 4 + r;
        const int idx = (qloc << 6) + ((chunk ^ (qloc & 7)) << 3) + sub;
        PhW[idx] = ph;
        PlW[idx] = pl;
      }
    }
#pragma unroll
    for (int r = 0; r < 4; ++r) {
      float sm = sum[r];
      sm += __shfl_xor(sm, 1);
      sm += __shfl_xor(sm, 2);
      sm += __shfl_xor(sm, 4);
      sm += __shfl_xor(sm, 8);
      l_run[r] = l_run[r] * al[r] + sm;
    }

    // ---- O rescale + PV ----
#pragma unroll
    for (int fo = 0; fo < 4; ++fo)
#pragma unroll
      for (int r = 0; r < 4; ++r) O[fo][r] *= al[r];

#pragma unroll
    for (int kj = 0; kj < 2; ++kj) {
      const int raddr = (l16 << 6) + (((kj * 4 + s) ^ (l16 & 7)) << 3);
      const bf16x8 pah = *(const bf16x8*)(PhW + raddr);
      const bf16x8 pal = *(const bf16x8*)(PlW + raddr);
#pragma unroll
      for (int fo = 0; fo < 4; ++fo) {
        const size_t va = ((bh << 6) + fo * 16 + l16) * (size_t)Ln + j0 + kj * 32 + s * 8;
        const bf16x8 vbh = *(const bf16x8*)(vTh + va);
        const bf16x8 vbl = *(const bf16x8*)(vTl + va);
        O[fo] = __builtin_amdgcn_mfma_f32_16x16x32_bf16(pah, vbh, O[fo], 0, 0, 0);
        O[fo] = __builtin_amdgcn_mfma_f32_16x16x32_bf16(pah, vbl, O[fo], 0, 0, 0);
        O[fo] = __builtin_amdgcn_mfma_f32_16x16x32_bf16(pal, vbh, O[fo], 0, 0, 0);
      }
    }
  }

  // ---- flash merge across the 4 waves ----
  if (l16 == 0) {
#pragma unroll
    for (int r = 0; r < 4; ++r) {
      mw[w][s * 4 + r] = m_run[r];
      lw[w][s * 4 + r] = l_run[r];
    }
  }
  __syncthreads();

  float fw[4];
#pragma unroll
  for (int r = 0; r < 4; ++r) {
    const int ql_ = s * 4 + r;
    const float g = fmaxf(fmaxf(mw[0][ql_], mw[1][ql_]), fmaxf(mw[2][ql_], mw[3][ql_]));
    fw[r] = __expf(m_run[r] - g);
  }
#pragma unroll
  for (int fo = 0; fo < 4; ++fo)
#pragma unroll
    for (int r = 0; r < 4; ++r)
      Om[w][s * 4 + r][fo * 16 + l16] = O[fo][r] * fw[r];
  __syncthreads();

  // final: 256 threads cover 16q x 64d (4 d each)
  {
    const int q = t >> 4;
    const int d0 = (t & 15) * 4;
    const float g = fmaxf(fmaxf(mw[0][q], mw[1][q]), fmaxf(mw[2][q], mw[3][q]));
    const float lt = lw[0][q] * __expf(mw[0][q] - g) + lw[1][q] * __expf(mw[1][q] - g) +
                     lw[2][q] * __expf(mw[2][q] - g) + lw[3][q] * __expf(mw[3][q] - g);
    const float inv = 1.0f / lt;
    float4 o4;
    o4.x = (Om[0][q][d0 + 0] + Om[1][q][d0 + 0] + Om[2][q][d0 + 0] + Om[3][q][d0 + 0]) * inv;
    o4.y = (Om[0][q][d0 + 1] + Om[1][q][d0 + 1] + Om[2][q][d0 + 1] + Om[3][q][d0 + 1]) * inv;
    o4.z = (Om[0][q][d0 + 2] + Om[1][q][d0 + 2] + Om[2][q][d0 + 2] + Om[3][q][d0 + 2]) * inv;
    o4.w = (Om[0][q][d0 + 3] + Om[1][q][d0 + 3] + Om[2][q][d0 + 3] + Om[3][q][d0 + 3]) * inv;
    *(float4*)(out + ((size_t)b * Ln + q0 + q) * DM + h * HD + d0) = o4;
  }
}

// ---------------------------------------------------------------------------
// kernel_launch
// ws layout: qrh qrl kh kl vTh vTl (bf16, QS each = 50.3 MB)
//            | Fs(f32,FSz) | Gs(f32,FSz) (33.6 MB)  = 83.9 MB total
// bf16 staging (xh|xl|wh|wl, 29.5 MB) aliases Fs/Gs: consumed by qkv_mfma
// before fg_gemm first writes Fs/Gs.
// ---------------------------------------------------------------------------
extern "C" void kernel_launch(void* const* d_in, const int* in_sizes, int n_in,
                              void* d_out, int out_size, void* d_ws, size_t ws_size,
                              hipStream_t stream) {
  const float* x    = (const float*)d_in[0];
  const float* prev = (const float*)d_in[1];
  const float* W    = (const float*)d_in[2];
  const float* rrb  = (const float*)d_in[3];
  const float* rwb  = (const float*)d_in[4];
  const float* R    = (const float*)d_in[5];
  const int*   skip = (const int*)d_in[6];

  float* out  = (float*)d_out;
  float* pout = out + (size_t)Bn * Ln * DM;

  float* ws = (float*)d_ws;
  unsigned short* qrh = (unsigned short*)ws;
  unsigned short* qrl = qrh + QS;
  unsigned short* kh  = qrl + QS;
  unsigned short* kl  = kh + QS;
  unsigned short* vTh = kl + QS;
  unsigned short* vTl = vTh + QS;
  float* Farr = ws + 3 * QS;  // 6 bf16 arrays = 3*QS floats
  float* Garr = Farr + FSz;

  unsigned short* xh = (unsigned short*)Farr;  // staging aliases Fs/Gs region
  unsigned short* xl = xh + QS;
  unsigned short* wwh = xl + QS;
  unsigned short* wwl = wwh + WN;

  conv_x<<<dim3(4096), 256, 0, stream>>>(x, xh, xl);
  conv_w<<<dim3(48, 16), 256, 0, stream>>>(W, wwh, wwl);
  qkv_mfma<<<dim3(24, 32), 256, 0, stream>>>(xh, xl, wwh, wwl, rrb,
                                             qrh, qrl, kh, kl, vTh, vTl);
  for (int b = 0; b < Bn; ++b) {
    fg_gemm<<<dim3(TL / 64, Ln / 64, Hn * 2), 256, 0, stream>>>(qrh, qrl, kh, kl, rrb, rwb, R,
                                                                Farr, Garr, b);
    attn_mfma<<<dim3(Ln / 16, Hn), 256, 0, stream>>>(qrh, qrl, kh, kl, vTh, vTl,
                                                     Farr, Garr, prev, skip, out, pout, b);
  }
}